// Round 1
// 377.498 us; speedup vs baseline: 1.1596x; 1.1596x over previous
//
#include <hip/hip_runtime.h>

typedef unsigned short u16;
typedef unsigned int u32;
typedef short bf16x8 __attribute__((ext_vector_type(8)));
typedef float f32x4 __attribute__((ext_vector_type(4)));

#define DD 1024
#define SS 1024
#define HH 16
#define HDIM 64
#define MODW 6144   // 6*DD

__device__ __forceinline__ float b2f(u16 h){ u32 u = ((u32)h)<<16; return __builtin_bit_cast(float,u); }
__device__ __forceinline__ u16 f2b(float f){
  u32 u = __builtin_bit_cast(u32,f);
  return (u16)((u + 0x7fffu + ((u>>16)&1u))>>16);   // RNE
}
// async global->LDS, 16B per lane; LDS dst must be wave-uniform base + lane*16 (m104)
__device__ __forceinline__ void gload16(const u16* g, u16* l){
  __builtin_amdgcn_global_load_lds((const __attribute__((address_space(1))) void*)g,
                                   (__attribute__((address_space(3))) void*)l, 16, 0, 0);
}

// ---------------- sentinel: zero fp32 output when ws_size insufficient ----------------
__global__ void k_zero(float* __restrict__ out){
  int i = blockIdx.x*256 + threadIdx.x;
  ((float4*)out)[i] = make_float4(0.f,0.f,0.f,0.f);
}

// ---------------- prep: all 4 weight transposes + adaLN mod in ONE launch ----------------
__device__ __forceinline__ void tcast_tile(const float* in, u16* out, int K, int N, int bx, int by){
  __shared__ float t[32][33];
  int n0 = bx*32, k0 = by*32;
  int tx = threadIdx.x & 31, ty = threadIdx.x >> 5;   // ty 0..7
  #pragma unroll
  for (int i=0;i<4;i++){
    int k = k0 + ty + i*8;
    t[ty+i*8][tx] = in[(size_t)k*N + n0 + tx];
  }
  __syncthreads();
  #pragma unroll
  for (int i=0;i<4;i++){
    int n = n0 + ty + i*8;
    out[(size_t)n*K + k0 + tx] = f2b(t[tx][ty+i*8]);
  }
}
__global__ void k_prep(const float* __restrict__ wqkv, const float* __restrict__ wout,
                       const float* __restrict__ w1, const float* __restrict__ w2,
                       u16* __restrict__ wqkvT, u16* __restrict__ woutT,
                       u16* __restrict__ w1T, u16* __restrict__ w2T,
                       const float* __restrict__ c, const float* __restrict__ aw,
                       const float* __restrict__ ab, float* __restrict__ mod){
  int bid = blockIdx.x;
  if (bid < 3072)       tcast_tile(wqkv, wqkvT, 1024, 3072, bid%96,  bid/96);
  else if (bid < 4096){ int t=bid-3072; tcast_tile(wout, woutT, 1024, 1024, t%32, t/32); }
  else if (bid < 8192){ int t=bid-4096; tcast_tile(w1,   w1T,   1024, 4096, t%128,t/128); }
  else if (bid < 12288){int t=bid-8192; tcast_tile(w2,   w2T,   4096, 1024, t%32, t/32); }
  else {
    int t = bid - 12288;                 // 0..95
    int n = (t%24)*256 + threadIdx.x;
    int bb = t/24;
    float acc = ab[n];
    #pragma unroll 4
    for (int k=0;k<128;k++) acc += c[bb*128+k]*aw[(size_t)k*MODW + n];
    mod[(size_t)bb*MODW + n] = acc;
  }
}

// ---------------- LayerNorm + modulate -> bf16 (row per block) ----------------
__global__ void k_ln_mod(const float* __restrict__ x, const float* __restrict__ w,
                         const float* __restrict__ mod, int shc, int scc,
                         u16* __restrict__ out){
  int row = blockIdx.x;            // 0..4095  (b*1024+s)
  int b = row >> 10;
  const float* xr = x + (size_t)row*DD;
  float4 v = ((const float4*)xr)[threadIdx.x];
  float s = v.x+v.y+v.z+v.w;
  float sq = v.x*v.x+v.y*v.y+v.z*v.z+v.w*v.w;
  #pragma unroll
  for (int o=32;o;o>>=1){ s += __shfl_xor(s,o); sq += __shfl_xor(sq,o); }
  __shared__ float ls[4], lq[4];
  int wid = threadIdx.x>>6, lane = threadIdx.x&63;
  if (lane==0){ ls[wid]=s; lq[wid]=sq; }
  __syncthreads();
  s = ls[0]+ls[1]+ls[2]+ls[3]; sq = lq[0]+lq[1]+lq[2]+lq[3];
  float mu = s*(1.f/DD);
  float var = sq*(1.f/DD) - mu*mu;
  float rs = rsqrtf(var + 1e-5f);
  int d0 = threadIdx.x*4;
  const float* mb = mod + (size_t)b*MODW;
  float y0 = ((v.x-mu)*rs*w[d0+0])*(1.f+mb[scc+d0+0]) + mb[shc+d0+0];
  float y1 = ((v.y-mu)*rs*w[d0+1])*(1.f+mb[scc+d0+1]) + mb[shc+d0+1];
  float y2 = ((v.z-mu)*rs*w[d0+2])*(1.f+mb[scc+d0+2]) + mb[shc+d0+2];
  float y3 = ((v.w-mu)*rs*w[d0+3])*(1.f+mb[scc+d0+3]) + mb[shc+d0+3];
  uint2 pk;
  pk.x = (u32)f2b(y0) | ((u32)f2b(y1)<<16);
  pk.y = (u32)f2b(y2) | ((u32)f2b(y3)<<16);
  ((uint2*)(out + (size_t)row*DD))[threadIdx.x] = pk;
}

// ---------------- GEMM: 256x256 tile, 512 thr / 8 waves (2x4), wave tile 128x64 ----------------
// 4-deep LDS ring of 32-wide K-chunks (4 x 32KB = 128KB, 1 block/CU).
// Fragment-ordered LDS via pre-swizzled global src -> conflict-free ds_read_b128 (T2-equivalent).
// Counted vmcnt(8): stage chunk t+3 while computing chunk t (T3+T4); setprio around MFMA (T5).
// One s_barrier per chunk. Ring safety: phase-t barrier follows each wave's vmcnt (chunk t
// globally resident) and each wave's phase-(t-1) lgkmcnt(0) (buf (t+3)&3 == (t-1)&3 fully read).
enum { EPI_QKV=0, EPI_GELU=2, EPI_PARTB=5 };

template<int EPI>
__launch_bounds__(512, 2)
__global__ void k_gemm256(const u16* __restrict__ A, const u16* __restrict__ Bt,
                          int M, int N, int K, int kstride,
                          const float* __restrict__ bias,
                          u16* __restrict__ outb,
                          const float* __restrict__ cosb, const float* __restrict__ sinb,
                          u16* __restrict__ qh, u16* __restrict__ kh, u16* __restrict__ vt){
  __shared__ __align__(16) u16 lds[4][2][8192];   // [ring][A|B][1024 frags x 8 elems]
  int tid = threadIdx.x, lane = tid & 63;
  int wid = tid >> 6, wr = wid >> 2, wc = wid & 3;    // 2x4 wave grid
  int bm = blockIdx.x*256, bn = blockIdx.y*256, z = blockIdx.z;
  f32x4 acc[8][4] = {};
  // staging source: frag f = l*512+tid -> row=(f>>6)*16+(tid&15), k=((tid>>4)&3)*8
  int srow = (tid>>6)*16 + (tid&15);
  int skk  = ((tid>>4)&3)*8;
  const u16* pa = A  + (size_t)(bm+srow)*kstride + (size_t)z*K + skk;
  const u16* pb = Bt + (size_t)(bn+srow)*kstride + (size_t)z*K + skk;
  size_t rh = (size_t)128*kstride;                 // +128 rows for second half (frags 512..1023)
  int nk = K >> 5;                                 // 32-wide chunks
  #pragma unroll
  for (int t=0; t<3; ++t){                         // prologue: chunks 0..2 in flight
    gload16(pa + t*32,      &lds[t][0][tid*8]);
    gload16(pa + rh + t*32, &lds[t][0][4096 + tid*8]);
    gload16(pb + t*32,      &lds[t][1][tid*8]);
    gload16(pb + rh + t*32, &lds[t][1][4096 + tid*8]);
  }
  for (int t=0; t<nk; ++t){
    const u16* lA = &lds[t&3][0][0];
    const u16* lB = &lds[t&3][1][0];
    int ahead = nk-1-t;
    if (ahead >= 2)      asm volatile("s_waitcnt vmcnt(8)" ::: "memory");  // chunk t landed
    else if (ahead == 1) asm volatile("s_waitcnt vmcnt(4)" ::: "memory");
    else                 asm volatile("s_waitcnt vmcnt(0)" ::: "memory");
    __builtin_amdgcn_s_barrier();
    if (t+3 < nk){                                 // stage chunk t+3 into buf freed last phase
      int u = t+3;
      gload16(pa + u*32,      &lds[u&3][0][tid*8]);
      gload16(pa + rh + u*32, &lds[u&3][0][4096 + tid*8]);
      gload16(pb + u*32,      &lds[u&3][1][tid*8]);
      gload16(pb + rh + u*32, &lds[u&3][1][4096 + tid*8]);
    }
    bf16x8 fa[8], fb[4];
    #pragma unroll
    for (int mi=0;mi<8;mi++) fa[mi] = *(const bf16x8*)(lA + ((wr*8+mi)*64 + lane)*8);
    #pragma unroll
    for (int ni=0;ni<4;ni++) fb[ni] = *(const bf16x8*)(lB + ((wc*4+ni)*64 + lane)*8);
    asm volatile("s_waitcnt lgkmcnt(0)" ::: "memory");
    __builtin_amdgcn_sched_barrier(0);             // rule #18: keep MFMA below the wait
    __builtin_amdgcn_s_setprio(1);
    #pragma unroll
    for (int mi=0;mi<8;mi++)
      #pragma unroll
      for (int ni=0;ni<4;ni++)
        acc[mi][ni] = __builtin_amdgcn_mfma_f32_16x16x32_bf16(fa[mi], fb[ni], acc[mi][ni], 0,0,0);
    __builtin_amdgcn_s_setprio(0);
  }
  // epilogue: D col=lane&15, row=(lane>>4)*4+r   [m89/m91]
  int ln = lane & 15;
  int rbase = bm + wr*128 + ((lane>>4)<<2);
  if (EPI == EPI_QKV){
    int cbg = bn + wc*64;         // wave spans exactly one head (64 cols)
    int ii = cbg >> 10;           // 0=q 1=k 2=v
    int hh = (cbg >> 6) & 15;
    if (ii == 2){
      // V: write TRANSPOSED vt(b,h,d,s) directly — 4 consecutive s per uint2
      #pragma unroll
      for (int mi=0;mi<8;mi++){
        int row = rbase + mi*16;
        int s = row & 1023, b = row >> 10;
        size_t ob = (size_t)(b*16+hh)*65536;
        #pragma unroll
        for (int ni=0;ni<4;ni++){
          int d = ni*16 + ln;
          u32 lo = (u32)f2b(acc[mi][ni][0]) | ((u32)f2b(acc[mi][ni][1])<<16);
          u32 hi = (u32)f2b(acc[mi][ni][2]) | ((u32)f2b(acc[mi][ni][3])<<16);
          *(uint2*)(vt + ob + (size_t)d*1024 + s) = make_uint2(lo,hi);
        }
      }
    } else {
      u16* dst = (ii==0) ? qh : kh;
      #pragma unroll
      for (int mi=0;mi<8;mi++){
        #pragma unroll
        for (int r=0;r<4;r++){
          int row = rbase + mi*16 + r;
          int s = row & 1023, b = row >> 10;
          size_t ob = ((size_t)(b*16+hh)*1024 + s)*64;
          #pragma unroll
          for (int ni=0;ni<2;ni++){
            int dlow = ni*16 + ln;                 // pairs (d, d+32) = frags (ni, ni+2)
            float cc = cosb[s*32 + dlow], sn = sinb[s*32 + dlow];
            float t1 = acc[mi][ni][r], t2 = acc[mi][ni+2][r];
            dst[ob + dlow]      = f2b(t1*cc - t2*sn);
            dst[ob + dlow + 32] = f2b(t2*cc + t1*sn);
          }
        }
      }
    }
    return;
  }
  if (EPI == EPI_PARTB){
    u16* po = outb + (size_t)z*M*N;
    #pragma unroll
    for (int mi=0;mi<8;mi++)
      #pragma unroll
      for (int ni=0;ni<4;ni++){
        int col = bn + wc*64 + ni*16 + ln;
        #pragma unroll
        for (int r=0;r<4;r++)
          po[(size_t)(rbase+mi*16+r)*N + col] = f2b(acc[mi][ni][r]);
      }
    return;
  }
  // EPI_GELU
  #pragma unroll
  for (int mi=0;mi<8;mi++)
    #pragma unroll
    for (int ni=0;ni<4;ni++){
      int col = bn + wc*64 + ni*16 + ln;
      float bb = bias[col];
      #pragma unroll
      for (int r=0;r<4;r++){
        float t = acc[mi][ni][r] + bb;
        float y = 0.7978845608f*(t + 0.044715f*t*t*t);
        y = fminf(fmaxf(y, -15.f), 15.f);
        float e = __expf(2.f*y);
        float g = 0.5f*t*(1.f + (e-1.f)/(e+1.f));
        outb[(size_t)(rbase+mi*16+r)*N + col] = f2b(g);
      }
    }
}

// ---------------- fused: split-K x2 bf16 reduce + residual + LN2 + modulate ----------------
__global__ void k_red_ln(const u16* __restrict__ part, const float* __restrict__ x,
                         const float* __restrict__ mod, const float* __restrict__ w,
                         float* __restrict__ x2, u16* __restrict__ act){
  int row = blockIdx.x;            // 0..4095
  int b = row >> 10;
  int tid = threadIdx.x;
  int col = tid*4;
  size_t base = (size_t)row*DD + col;
  const size_t MN = (size_t)4096*1024;
  uint2 p0 = *(const uint2*)(part + base);
  uint2 p1 = *(const uint2*)(part + MN + base);
  const float* mb = mod + (size_t)b*MODW;
  float4 g = *(const float4*)(mb + 2*DD + col);
  float4 rr = *(const float4*)(x + base);
  float4 v;
  v.x = rr.x + g.x*(b2f((u16)p0.x)      + b2f((u16)p1.x));
  v.y = rr.y + g.y*(b2f((u16)(p0.x>>16))+ b2f((u16)(p1.x>>16)));
  v.z = rr.z + g.z*(b2f((u16)p0.y)      + b2f((u16)p1.y));
  v.w = rr.w + g.w*(b2f((u16)(p0.y>>16))+ b2f((u16)(p1.y>>16)));
  *(float4*)(x2 + base) = v;
  float s = v.x+v.y+v.z+v.w;
  float sq = v.x*v.x+v.y*v.y+v.z*v.z+v.w*v.w;
  #pragma unroll
  for (int o=32;o;o>>=1){ s += __shfl_xor(s,o); sq += __shfl_xor(sq,o); }
  __shared__ float ls[4], lq[4];
  int wid = tid>>6, lane = tid&63;
  if (lane==0){ ls[wid]=s; lq[wid]=sq; }
  __syncthreads();
  s = ls[0]+ls[1]+ls[2]+ls[3]; sq = lq[0]+lq[1]+lq[2]+lq[3];
  float mu = s*(1.f/DD);
  float var = sq*(1.f/DD) - mu*mu;
  float rs = rsqrtf(var + 1e-5f);
  float y0 = ((v.x-mu)*rs*w[col+0])*(1.f+mb[4*DD+col+0]) + mb[3*DD+col+0];
  float y1 = ((v.y-mu)*rs*w[col+1])*(1.f+mb[4*DD+col+1]) + mb[3*DD+col+1];
  float y2 = ((v.z-mu)*rs*w[col+2])*(1.f+mb[4*DD+col+2]) + mb[3*DD+col+2];
  float y3 = ((v.w-mu)*rs*w[col+3])*(1.f+mb[4*DD+col+3]) + mb[3*DD+col+3];
  uint2 pk;
  pk.x = (u32)f2b(y0) | ((u32)f2b(y1)<<16);
  pk.y = (u32)f2b(y2) | ((u32)f2b(y3)<<16);
  *(uint2*)(act + base) = pk;
}

// ---------------- split-K reduce (bf16 partials, NCH=4): out = resid + gate*(sum + bias) ----------------
__global__ void k_reduce4b(const u16* __restrict__ part, size_t MN,
                           const float* __restrict__ resid,
                           const float* __restrict__ mod, int gate_off,
                           const float* __restrict__ bias,
                           float* __restrict__ out){
  int i = blockIdx.x*256 + threadIdx.x;   // 4-element index
  int e = i<<2;
  int col = e & 1023;
  int row = e >> 10;
  int b = row >> 10;
  float4 s = make_float4(0.f,0.f,0.f,0.f);
  #pragma unroll
  for (int z=0; z<4; z++){
    uint2 p = ((const uint2*)(part + (size_t)z*MN))[i];
    s.x += b2f((u16)p.x); s.y += b2f((u16)(p.x>>16));
    s.z += b2f((u16)p.y); s.w += b2f((u16)(p.y>>16));
  }
  float4 bb = *(const float4*)(bias + col);
  s.x+=bb.x; s.y+=bb.y; s.z+=bb.z; s.w+=bb.w;
  float4 g = *(const float4*)(mod + (size_t)b*MODW + gate_off + col);
  float4 rr = ((const float4*)resid)[i];
  float4 o;
  o.x = rr.x + g.x*s.x; o.y = rr.y + g.y*s.y;
  o.z = rr.z + g.z*s.z; o.w = rr.w + g.w*s.w;
  ((float4*)out)[i] = o;
}

// ---------------- MFMA flash attention ----------------
__launch_bounds__(256)
__global__ void k_attn(const u16* __restrict__ qh, const u16* __restrict__ kh,
                       const u16* __restrict__ vt, u16* __restrict__ attn){
  int blk = blockIdx.x;           // 1024 = 64 bh x 16 qtiles
  int bh = blk >> 4;
  int qt = blk & 15;
  int tid = threadIdx.x, lane = tid&63, wid = tid>>6;
  int ln = lane&15, kg = lane>>4;
  __shared__ __align__(16) u16 Ks[64*72];
  __shared__ __align__(16) u16 Vs[64*72];
  __shared__ __align__(16) float ps[4][16*72];
  const size_t hb = (size_t)bh*SS*HDIM;

  int qrow = qt*64 + wid*16 + ln;
  const u16* qp = qh + hb + (size_t)qrow*64 + kg*8;
  bf16x8 qf0 = *(const bf16x8*)qp;
  bf16x8 qf1 = *(const bf16x8*)(qp + 32);

  float m[4], l[4];
  f32x4 oc[4] = {};
  #pragma unroll
  for (int r=0;r<4;r++){ m[r]=-1e30f; l[r]=0.f; }
  float* psw = ps[wid];

  for (int kt=0; kt<16; ++kt){
    __syncthreads();
    {
      int row = tid>>2, c = tid&3;
      const u16* gk = kh + hb + (size_t)(kt*64+row)*64 + c*16;
      *(uint4*)(Ks + row*72 + c*16)     = *(const uint4*)gk;
      *(uint4*)(Ks + row*72 + c*16 + 8) = *(const uint4*)(gk+8);
      const u16* gv = vt + hb + (size_t)row*1024 + kt*64 + c*16;
      *(uint4*)(Vs + row*72 + c*16)     = *(const uint4*)gv;
      *(uint4*)(Vs + row*72 + c*16 + 8) = *(const uint4*)(gv+8);
    }
    __syncthreads();

    f32x4 sc[4] = {};
    #pragma unroll
    for (int c=0;c<4;c++){
      bf16x8 kf0 = *(const bf16x8*)(Ks + (c*16+ln)*72 + kg*8);
      bf16x8 kf1 = *(const bf16x8*)(Ks + (c*16+ln)*72 + kg*8 + 32);
      sc[c] = __builtin_amdgcn_mfma_f32_16x16x32_bf16(qf0, kf0, sc[c], 0,0,0);
      sc[c] = __builtin_amdgcn_mfma_f32_16x16x32_bf16(qf1, kf1, sc[c], 0,0,0);
    }
    #pragma unroll
    for (int r=0;r<4;r++){
      float s0 = sc[0][r]*0.125f, s1 = sc[1][r]*0.125f;
      float s2 = sc[2][r]*0.125f, s3 = sc[3][r]*0.125f;
      float mx = fmaxf(fmaxf(s0,s1), fmaxf(s2,s3));
      #pragma unroll
      for (int off=8;off;off>>=1) mx = fmaxf(mx, __shfl_xor(mx, off));
      float mn = fmaxf(m[r], mx);
      float al = __expf(m[r]-mn);
      m[r] = mn;
      float p0=__expf(s0-mn), p1=__expf(s1-mn), p2=__expf(s2-mn), p3=__expf(s3-mn);
      float sum = (p0+p1)+(p2+p3);
      #pragma unroll
      for (int off=8;off;off>>=1) sum += __shfl_xor(sum, off);
      l[r] = l[r]*al + sum;
      #pragma unroll
      for (int c=0;c<4;c++) oc[c][r] *= al;
      int ro = (kg*4+r)*72;
      psw[ro +  0 + ln] = p0;
      psw[ro + 16 + ln] = p1;
      psw[ro + 32 + ln] = p2;
      psw[ro + 48 + ln] = p3;
    }
    #pragma unroll
    for (int kc=0; kc<2; ++kc){
      const float* pr = psw + ln*72 + kg*8 + kc*32;
      f32x4 a0 = *(const f32x4*)pr;
      f32x4 a1 = *(const f32x4*)(pr+4);
      bf16x8 af;
      af[0]=f2b(a0[0]); af[1]=f2b(a0[1]); af[2]=f2b(a0[2]); af[3]=f2b(a0[3]);
      af[4]=f2b(a1[0]); af[5]=f2b(a1[1]); af[6]=f2b(a1[2]); af[7]=f2b(a1[3]);
      #pragma unroll
      for (int c=0;c<4;c++){
        bf16x8 vf = *(const bf16x8*)(Vs + (c*16+ln)*72 + kg*8 + kc*32);
        oc[c] = __builtin_amdgcn_mfma_f32_16x16x32_bf16(af, vf, oc[c], 0,0,0);
      }
    }
  }
  int b = bh >> 4, h = bh & 15;
  #pragma unroll
  for (int r=0;r<4;r++){
    int srow = qt*64 + wid*16 + kg*4 + r;
    float inv = 1.f/l[r];
    u16* op = attn + (size_t)(b*1024+srow)*DD + h*64;
    #pragma unroll
    for (int c=0;c<4;c++) op[c*16+ln] = f2b(oc[c][r]*inv);
  }
}

// ---------------- launch ----------------
extern "C" void kernel_launch(void* const* d_in, const int* in_sizes, int n_in,
                              void* d_out, int out_size, void* d_ws, size_t ws_size,
                              hipStream_t stream){
  const float* x   = (const float*)d_in[0];
  const float* c   = (const float*)d_in[1];
  const float* n1w = (const float*)d_in[2];
  const float* n2w = (const float*)d_in[3];
  const float* wqkv= (const float*)d_in[4];
  const float* wout= (const float*)d_in[5];
  const float* w1  = (const float*)d_in[6];
  const float* b1  = (const float*)d_in[7];
  const float* w2  = (const float*)d_in[8];
  const float* b2  = (const float*)d_in[9];
  const float* aw  = (const float*)d_in[10];
  const float* ab  = (const float*)d_in[11];
  const float* cosb= (const float*)d_in[12];
  const float* sinb= (const float*)d_in[13];

  const size_t REQ = 117538816;
  if (ws_size < REQ){
    k_zero<<<4096,256,0,stream>>>((float*)d_out);   // sentinel: absmax==5.03 => ws too small
    return;
  }
  char* ws = (char*)d_ws;
  u16*   wqkvT = (u16*)(ws + 0);
  u16*   woutT = (u16*)(ws + 6291456);
  u16*   act   = (u16*)(ws + 8388608);
  float* mod   = (float*)(ws + 16777216);
  float* x2    = (float*)(ws + 16875520);
  u16*   qh    = (u16*)(ws + 16875520);
  u16*   kh    = (u16*)(ws + 25264128);
  u16*   vt    = (u16*)(ws + 33652736);    // 8 MB (b,h,d,s), written by QKV epilogue
  u16*   part2b= (u16*)(ws + 33652736);    // 16 MB bf16 (over vt, dead after attn)
  u16*   hbuf  = (u16*)(ws + 33652736);    // 32 MB bf16 (after red_ln)
  u16*   w1T   = (u16*)(ws + 67207168);
  u16*   w2T   = (u16*)(ws + 75595776);
  u16*   part4b= (u16*)(ws + 83984384);    // 32 MB bf16

  k_prep<<<12384,256,0,stream>>>(wqkv, wout, w1, w2, wqkvT, woutT, w1T, w2T, c, aw, ab, mod);
  k_ln_mod<<<4096,256,0,stream>>>(x, n1w, mod, 0*DD, 1*DD, act);
  k_gemm256<EPI_QKV ><<<dim3(16,12,1),512,0,stream>>>(act, wqkvT, 4096,3072,1024,1024,
        nullptr, nullptr, cosb, sinb, qh, kh, vt);
  k_attn<<<1024,256,0,stream>>>(qh, kh, vt, act);
  // attn proj: split-K x2, bf16 partials, fused reduce+resid+LN2+modulate
  k_gemm256<EPI_PARTB><<<dim3(16,4,2),512,0,stream>>>(act, woutT, 4096,1024,512,1024,
        nullptr, part2b, nullptr, nullptr, nullptr, nullptr, nullptr);
  k_red_ln<<<4096,256,0,stream>>>(part2b, x, mod, n2w, x2, act);
  k_gemm256<EPI_GELU><<<dim3(16,16,1),512,0,stream>>>(act, w1T, 4096,4096,1024,1024,
        b1, hbuf, nullptr, nullptr, nullptr, nullptr, nullptr);
  // mlp2: split-K x4 (bf16 partials), reduce -> d_out
  k_gemm256<EPI_PARTB><<<dim3(16,4,4),512,0,stream>>>(hbuf, w2T, 4096,1024,1024,4096,
        nullptr, part4b, nullptr, nullptr, nullptr, nullptr, nullptr);
  k_reduce4b<<<4096,256,0,stream>>>(part4b, (size_t)4096*1024, x2, mod, 5*DD, b2, (float*)d_out);
}

// Round 2
// 351.538 us; speedup vs baseline: 1.2453x; 1.0738x over previous
//
#include <hip/hip_runtime.h>

typedef unsigned short u16;
typedef unsigned int u32;
typedef short bf16x8 __attribute__((ext_vector_type(8)));
typedef float f32x4 __attribute__((ext_vector_type(4)));

#define DD 1024
#define SS 1024
#define HH 16
#define HDIM 64
#define MODW 6144   // 6*DD

__device__ __forceinline__ float b2f(u16 h){ u32 u = ((u32)h)<<16; return __builtin_bit_cast(float,u); }
__device__ __forceinline__ u16 f2b(float f){
  u32 u = __builtin_bit_cast(u32,f);
  return (u16)((u + 0x7fffu + ((u>>16)&1u))>>16);   // RNE
}
__device__ __forceinline__ u32 cvtpk(float a, float b){
  u32 r; asm("v_cvt_pk_bf16_f32 %0, %1, %2" : "=v"(r) : "v"(a), "v"(b)); return r;  // RNE pair
}
// async global->LDS, 16B per lane; LDS dst must be wave-uniform base + lane*16 (m104)
__device__ __forceinline__ void gload16(const u16* g, u16* l){
  __builtin_amdgcn_global_load_lds((const __attribute__((address_space(1))) void*)g,
                                   (__attribute__((address_space(3))) void*)l, 16, 0, 0);
}

// ---------------- sentinel: zero fp32 output when ws_size insufficient ----------------
__global__ void k_zero(float* __restrict__ out){
  int i = blockIdx.x*256 + threadIdx.x;
  ((float4*)out)[i] = make_float4(0.f,0.f,0.f,0.f);
}

// ---------------- prep: all 4 weight transposes + adaLN mod in ONE launch ----------------
__device__ __forceinline__ void tcast_tile(const float* in, u16* out, int K, int N, int bx, int by){
  __shared__ float t[32][33];
  int n0 = bx*32, k0 = by*32;
  int tx = threadIdx.x & 31, ty = threadIdx.x >> 5;   // ty 0..7
  #pragma unroll
  for (int i=0;i<4;i++){
    int k = k0 + ty + i*8;
    t[ty+i*8][tx] = in[(size_t)k*N + n0 + tx];
  }
  __syncthreads();
  #pragma unroll
  for (int i=0;i<4;i++){
    int n = n0 + ty + i*8;
    out[(size_t)n*K + k0 + tx] = f2b(t[tx][ty+i*8]);
  }
}
__global__ void k_prep(const float* __restrict__ wqkv, const float* __restrict__ wout,
                       const float* __restrict__ w1, const float* __restrict__ w2,
                       u16* __restrict__ wqkvT, u16* __restrict__ woutT,
                       u16* __restrict__ w1T, u16* __restrict__ w2T,
                       const float* __restrict__ c, const float* __restrict__ aw,
                       const float* __restrict__ ab, float* __restrict__ mod){
  int bid = blockIdx.x;
  if (bid < 3072)       tcast_tile(wqkv, wqkvT, 1024, 3072, bid%96,  bid/96);
  else if (bid < 4096){ int t=bid-3072; tcast_tile(wout, woutT, 1024, 1024, t%32, t/32); }
  else if (bid < 8192){ int t=bid-4096; tcast_tile(w1,   w1T,   1024, 4096, t%128,t/128); }
  else if (bid < 12288){int t=bid-8192; tcast_tile(w2,   w2T,   4096, 1024, t%32, t/32); }
  else {
    int t = bid - 12288;                 // 0..95
    int n = (t%24)*256 + threadIdx.x;
    int bb = t/24;
    float acc = ab[n];
    #pragma unroll 4
    for (int k=0;k<128;k++) acc += c[bb*128+k]*aw[(size_t)k*MODW + n];
    mod[(size_t)bb*MODW + n] = acc;
  }
}

// ---------------- LayerNorm + modulate -> bf16 (row per block) ----------------
__global__ void k_ln_mod(const float* __restrict__ x, const float* __restrict__ w,
                         const float* __restrict__ mod, int shc, int scc,
                         u16* __restrict__ out){
  int row = blockIdx.x;            // 0..4095  (b*1024+s)
  int b = row >> 10;
  const float* xr = x + (size_t)row*DD;
  float4 v = ((const float4*)xr)[threadIdx.x];
  float s = v.x+v.y+v.z+v.w;
  float sq = v.x*v.x+v.y*v.y+v.z*v.z+v.w*v.w;
  #pragma unroll
  for (int o=32;o;o>>=1){ s += __shfl_xor(s,o); sq += __shfl_xor(sq,o); }
  __shared__ float ls[4], lq[4];
  int wid = threadIdx.x>>6, lane = threadIdx.x&63;
  if (lane==0){ ls[wid]=s; lq[wid]=sq; }
  __syncthreads();
  s = ls[0]+ls[1]+ls[2]+ls[3]; sq = lq[0]+lq[1]+lq[2]+lq[3];
  float mu = s*(1.f/DD);
  float var = sq*(1.f/DD) - mu*mu;
  float rs = rsqrtf(var + 1e-5f);
  int d0 = threadIdx.x*4;
  const float* mb = mod + (size_t)b*MODW;
  float y0 = ((v.x-mu)*rs*w[d0+0])*(1.f+mb[scc+d0+0]) + mb[shc+d0+0];
  float y1 = ((v.y-mu)*rs*w[d0+1])*(1.f+mb[scc+d0+1]) + mb[shc+d0+1];
  float y2 = ((v.z-mu)*rs*w[d0+2])*(1.f+mb[scc+d0+2]) + mb[shc+d0+2];
  float y3 = ((v.w-mu)*rs*w[d0+3])*(1.f+mb[scc+d0+3]) + mb[shc+d0+3];
  uint2 pk;
  pk.x = (u32)f2b(y0) | ((u32)f2b(y1)<<16);
  pk.y = (u32)f2b(y2) | ((u32)f2b(y3)<<16);
  ((uint2*)(out + (size_t)row*DD))[threadIdx.x] = pk;
}

// ---------------- GEMM: 256x256 tile, 512 thr / 8 waves (2x4), wave tile 128x64 ----------------
// 4-deep LDS ring of 32-wide K-chunks (4 x 32KB = 128KB, 1 block/CU).
// Fragment-ordered LDS via pre-swizzled global src -> conflict-free ds_read_b128 (T2-equivalent).
// Counted vmcnt(8): stage chunk t+3 while computing chunk t (T3+T4); setprio around MFMA (T5).
enum { EPI_QKV=0, EPI_GELU=2, EPI_PARTB=5 };

template<int EPI>
__launch_bounds__(512, 2)
__global__ void k_gemm256(const u16* __restrict__ A, const u16* __restrict__ Bt,
                          int M, int N, int K, int kstride,
                          const float* __restrict__ bias,
                          u16* __restrict__ outb,
                          const float* __restrict__ cosb, const float* __restrict__ sinb,
                          u16* __restrict__ qh, u16* __restrict__ kh, u16* __restrict__ vt){
  __shared__ __align__(16) u16 lds[4][2][8192];   // [ring][A|B][1024 frags x 8 elems]
  int tid = threadIdx.x, lane = tid & 63;
  int wid = tid >> 6, wr = wid >> 2, wc = wid & 3;    // 2x4 wave grid
  int bm = blockIdx.x*256, bn = blockIdx.y*256, z = blockIdx.z;
  f32x4 acc[8][4] = {};
  // staging source: frag f = l*512+tid -> row=(f>>6)*16+(tid&15), k=((tid>>4)&3)*8
  int srow = (tid>>6)*16 + (tid&15);
  int skk  = ((tid>>4)&3)*8;
  const u16* pa = A  + (size_t)(bm+srow)*kstride + (size_t)z*K + skk;
  const u16* pb = Bt + (size_t)(bn+srow)*kstride + (size_t)z*K + skk;
  size_t rh = (size_t)128*kstride;                 // +128 rows for second half (frags 512..1023)
  int nk = K >> 5;                                 // 32-wide chunks
  #pragma unroll
  for (int t=0; t<3; ++t){                         // prologue: chunks 0..2 in flight
    gload16(pa + t*32,      &lds[t][0][tid*8]);
    gload16(pa + rh + t*32, &lds[t][0][4096 + tid*8]);
    gload16(pb + t*32,      &lds[t][1][tid*8]);
    gload16(pb + rh + t*32, &lds[t][1][4096 + tid*8]);
  }
  for (int t=0; t<nk; ++t){
    const u16* lA = &lds[t&3][0][0];
    const u16* lB = &lds[t&3][1][0];
    int ahead = nk-1-t;
    if (ahead >= 2)      asm volatile("s_waitcnt vmcnt(8)" ::: "memory");  // chunk t landed
    else if (ahead == 1) asm volatile("s_waitcnt vmcnt(4)" ::: "memory");
    else                 asm volatile("s_waitcnt vmcnt(0)" ::: "memory");
    __builtin_amdgcn_s_barrier();
    if (t+3 < nk){                                 // stage chunk t+3 into buf freed last phase
      int u = t+3;
      gload16(pa + u*32,      &lds[u&3][0][tid*8]);
      gload16(pa + rh + u*32, &lds[u&3][0][4096 + tid*8]);
      gload16(pb + u*32,      &lds[u&3][1][tid*8]);
      gload16(pb + rh + u*32, &lds[u&3][1][4096 + tid*8]);
    }
    bf16x8 fa[8], fb[4];
    #pragma unroll
    for (int mi=0;mi<8;mi++) fa[mi] = *(const bf16x8*)(lA + ((wr*8+mi)*64 + lane)*8);
    #pragma unroll
    for (int ni=0;ni<4;ni++) fb[ni] = *(const bf16x8*)(lB + ((wc*4+ni)*64 + lane)*8);
    asm volatile("s_waitcnt lgkmcnt(0)" ::: "memory");
    __builtin_amdgcn_sched_barrier(0);             // rule #18: keep MFMA below the wait
    __builtin_amdgcn_s_setprio(1);
    #pragma unroll
    for (int mi=0;mi<8;mi++)
      #pragma unroll
      for (int ni=0;ni<4;ni++)
        acc[mi][ni] = __builtin_amdgcn_mfma_f32_16x16x32_bf16(fa[mi], fb[ni], acc[mi][ni], 0,0,0);
    __builtin_amdgcn_s_setprio(0);
  }
  // epilogue: D col=lane&15, row=(lane>>4)*4+r   [m89/m91]
  int ln = lane & 15;
  int rbase = bm + wr*128 + ((lane>>4)<<2);
  if (EPI == EPI_QKV){
    int cbg = bn + wc*64;         // wave spans exactly one head (64 cols)
    int ii = cbg >> 10;           // 0=q 1=k 2=v
    int hh = (cbg >> 6) & 15;
    if (ii == 2){
      // V: write TRANSPOSED vt(b,h,d,s) directly — 4 consecutive s per uint2
      #pragma unroll
      for (int mi=0;mi<8;mi++){
        int row = rbase + mi*16;
        int s = row & 1023, b = row >> 10;
        size_t ob = (size_t)(b*16+hh)*65536;
        #pragma unroll
        for (int ni=0;ni<4;ni++){
          int d = ni*16 + ln;
          u32 lo = (u32)f2b(acc[mi][ni][0]) | ((u32)f2b(acc[mi][ni][1])<<16);
          u32 hi = (u32)f2b(acc[mi][ni][2]) | ((u32)f2b(acc[mi][ni][3])<<16);
          *(uint2*)(vt + ob + (size_t)d*1024 + s) = make_uint2(lo,hi);
        }
      }
    } else {
      u16* dst = (ii==0) ? qh : kh;
      float qs = (ii==0) ? 0.125f : 1.0f;   // fold softmax scale into Q (exact: pow2)
      #pragma unroll
      for (int mi=0;mi<8;mi++){
        #pragma unroll
        for (int r=0;r<4;r++){
          int row = rbase + mi*16 + r;
          int s = row & 1023, b = row >> 10;
          size_t ob = ((size_t)(b*16+hh)*1024 + s)*64;
          #pragma unroll
          for (int ni=0;ni<2;ni++){
            int dlow = ni*16 + ln;                 // pairs (d, d+32) = frags (ni, ni+2)
            float cc = cosb[s*32 + dlow], sn = sinb[s*32 + dlow];
            float t1 = acc[mi][ni][r], t2 = acc[mi][ni+2][r];
            dst[ob + dlow]      = f2b((t1*cc - t2*sn)*qs);
            dst[ob + dlow + 32] = f2b((t2*cc + t1*sn)*qs);
          }
        }
      }
    }
    return;
  }
  if (EPI == EPI_PARTB){
    u16* po = outb + (size_t)z*M*N;
    #pragma unroll
    for (int mi=0;mi<8;mi++)
      #pragma unroll
      for (int ni=0;ni<4;ni++){
        int col = bn + wc*64 + ni*16 + ln;
        #pragma unroll
        for (int r=0;r<4;r++)
          po[(size_t)(rbase+mi*16+r)*N + col] = f2b(acc[mi][ni][r]);
      }
    return;
  }
  // EPI_GELU
  #pragma unroll
  for (int mi=0;mi<8;mi++)
    #pragma unroll
    for (int ni=0;ni<4;ni++){
      int col = bn + wc*64 + ni*16 + ln;
      float bb = bias[col];
      #pragma unroll
      for (int r=0;r<4;r++){
        float t = acc[mi][ni][r] + bb;
        float y = 0.7978845608f*(t + 0.044715f*t*t*t);
        y = fminf(fmaxf(y, -15.f), 15.f);
        float e = __expf(2.f*y);
        float g = 0.5f*t*(1.f + (e-1.f)/(e+1.f));
        outb[(size_t)(rbase+mi*16+r)*N + col] = f2b(g);
      }
    }
}

// ---------------- fused: split-K x2 bf16 reduce + residual + LN2 + modulate ----------------
__global__ void k_red_ln(const u16* __restrict__ part, const float* __restrict__ x,
                         const float* __restrict__ mod, const float* __restrict__ w,
                         float* __restrict__ x2, u16* __restrict__ act){
  int row = blockIdx.x;            // 0..4095
  int b = row >> 10;
  int tid = threadIdx.x;
  int col = tid*4;
  size_t base = (size_t)row*DD + col;
  const size_t MN = (size_t)4096*1024;
  uint2 p0 = *(const uint2*)(part + base);
  uint2 p1 = *(const uint2*)(part + MN + base);
  const float* mb = mod + (size_t)b*MODW;
  float4 g = *(const float4*)(mb + 2*DD + col);
  float4 rr = *(const float4*)(x + base);
  float4 v;
  v.x = rr.x + g.x*(b2f((u16)p0.x)      + b2f((u16)p1.x));
  v.y = rr.y + g.y*(b2f((u16)(p0.x>>16))+ b2f((u16)(p1.x>>16)));
  v.z = rr.z + g.z*(b2f((u16)p0.y)      + b2f((u16)p1.y));
  v.w = rr.w + g.w*(b2f((u16)(p0.y>>16))+ b2f((u16)(p1.y>>16)));
  *(float4*)(x2 + base) = v;
  float s = v.x+v.y+v.z+v.w;
  float sq = v.x*v.x+v.y*v.y+v.z*v.z+v.w*v.w;
  #pragma unroll
  for (int o=32;o;o>>=1){ s += __shfl_xor(s,o); sq += __shfl_xor(sq,o); }
  __shared__ float ls[4], lq[4];
  int wid = tid>>6, lane = tid&63;
  if (lane==0){ ls[wid]=s; lq[wid]=sq; }
  __syncthreads();
  s = ls[0]+ls[1]+ls[2]+ls[3]; sq = lq[0]+lq[1]+lq[2]+lq[3];
  float mu = s*(1.f/DD);
  float var = sq*(1.f/DD) - mu*mu;
  float rs = rsqrtf(var + 1e-5f);
  float y0 = ((v.x-mu)*rs*w[col+0])*(1.f+mb[4*DD+col+0]) + mb[3*DD+col+0];
  float y1 = ((v.y-mu)*rs*w[col+1])*(1.f+mb[4*DD+col+1]) + mb[3*DD+col+1];
  float y2 = ((v.z-mu)*rs*w[col+2])*(1.f+mb[4*DD+col+2]) + mb[3*DD+col+2];
  float y3 = ((v.w-mu)*rs*w[col+3])*(1.f+mb[4*DD+col+3]) + mb[3*DD+col+3];
  uint2 pk;
  pk.x = (u32)f2b(y0) | ((u32)f2b(y1)<<16);
  pk.y = (u32)f2b(y2) | ((u32)f2b(y3)<<16);
  *(uint2*)(act + base) = pk;
}

// ---------------- split-K reduce (bf16 partials, NCH=4): out = resid + gate*(sum + bias) ----------------
__global__ void k_reduce4b(const u16* __restrict__ part, size_t MN,
                           const float* __restrict__ resid,
                           const float* __restrict__ mod, int gate_off,
                           const float* __restrict__ bias,
                           float* __restrict__ out){
  int i = blockIdx.x*256 + threadIdx.x;   // 4-element index
  int e = i<<2;
  int col = e & 1023;
  int row = e >> 10;
  int b = row >> 10;
  float4 s = make_float4(0.f,0.f,0.f,0.f);
  #pragma unroll
  for (int z=0; z<4; z++){
    uint2 p = ((const uint2*)(part + (size_t)z*MN))[i];
    s.x += b2f((u16)p.x); s.y += b2f((u16)(p.x>>16));
    s.z += b2f((u16)p.y); s.w += b2f((u16)(p.y>>16));
  }
  float4 bb = *(const float4*)(bias + col);
  s.x+=bb.x; s.y+=bb.y; s.z+=bb.z; s.w+=bb.w;
  float4 g = *(const float4*)(mod + (size_t)b*MODW + gate_off + col);
  float4 rr = ((const float4*)resid)[i];
  float4 o;
  o.x = rr.x + g.x*s.x; o.y = rr.y + g.y*s.y;
  o.z = rr.z + g.z*s.z; o.w = rr.w + g.w*s.w;
  ((float4*)out)[i] = o;
}

// ---------------- MFMA flash attention: swapped QK^T, in-register softmax ----------------
// q = ln lane-local (mfma(K,Q)); P redistributed to PV A-frags via 16 bpermutes (no ps LDS).
// K/V double-buffered via global_load_lds, counted vmcnt(4), linear LDS dst with
// pre-swizzled global source; reads use slot ^ (row&7) (rule #21 both-sides swizzle).
__launch_bounds__(256, 4)
__global__ void k_attn(const u16* __restrict__ qh, const u16* __restrict__ kh,
                       const u16* __restrict__ vt, u16* __restrict__ attn){
  int blk = blockIdx.x;           // 1024 = 64 bh x 16 qtiles
  int bh = blk >> 4;
  int qt = blk & 15;
  int tid = threadIdx.x, lane = tid&63, wid = tid>>6;
  int ln = lane&15, kg = lane>>4;
  int sw = ln & 7;
  __shared__ __align__(16) u16 KV[2][2][4096];   // [buf][K|V][64 rows x 8 slots x 8 u16]
  const size_t hb = (size_t)bh*SS*HDIM;

  // Q as B-operand: lane holds Q[q=qt*64+wid*16+ln][d = kg*8+e (+32)]; Q pre-scaled by 0.125
  int qrow = qt*64 + wid*16 + ln;
  const u16* qp = qh + hb + (size_t)qrow*64 + kg*8;
  bf16x8 qf0 = *(const bf16x8*)qp;
  bf16x8 qf1 = *(const bf16x8*)(qp + 32);

  // staging: 512 16B-slots per array; thread covers w0i, w1i; logical slot = (w&7)^(row&7)
  int w0i = wid*64 + lane, w1i = w0i + 256;
  int r0 = w0i>>3, sl0 = (w0i&7) ^ (r0&7);
  int r1 = w1i>>3, sl1 = (w1i&7) ^ (r1&7);
  const u16* gk0 = kh + hb + (size_t)r0*64 + sl0*8;
  const u16* gk1 = kh + hb + (size_t)r1*64 + sl1*8;
  const u16* gv0 = vt + hb + (size_t)r0*1024 + sl0*8;
  const u16* gv1 = vt + hb + (size_t)r1*1024 + sl1*8;

  float mrun = -1e30f, lrun = 0.f;
  f32x4 oc[4] = {};

  gload16(gk0, &KV[0][0][w0i*8]);            // prologue: tile 0
  gload16(gk1, &KV[0][0][w1i*8]);
  gload16(gv0, &KV[0][1][w0i*8]);
  gload16(gv1, &KV[0][1][w1i*8]);

  for (int kt=0; kt<16; ++kt){
    int buf = kt & 1;
    __builtin_amdgcn_s_barrier();            // barrier_A: all reads of buf^1 (tile kt-1) done
    asm volatile("" ::: "memory");
    if (kt < 15){
      int u = kt+1;
      gload16(gk0 + u*4096, &KV[buf^1][0][w0i*8]);
      gload16(gk1 + u*4096, &KV[buf^1][0][w1i*8]);
      gload16(gv0 + u*64,   &KV[buf^1][1][w0i*8]);
      gload16(gv1 + u*64,   &KV[buf^1][1][w1i*8]);
      asm volatile("s_waitcnt vmcnt(4)" ::: "memory");   // tile kt resident, kt+1 in flight
    } else {
      asm volatile("s_waitcnt vmcnt(0)" ::: "memory");
    }
    __builtin_amdgcn_s_barrier();            // barrier_B: tile kt visible to all waves
    const u16* Kb = KV[buf][0];
    const u16* Vb = KV[buf][1];

    // swapped QK^T: sc[c] lane holds S[q=ln][k=c*16+4*kg+r] (scale folded into Q)
    f32x4 sc[4];
    #pragma unroll
    for (int c=0;c<4;c++){
      const u16* kr = Kb + (c*16+ln)*64;
      bf16x8 kf0 = *(const bf16x8*)(kr + (((kg  )^sw)<<3));
      bf16x8 kf1 = *(const bf16x8*)(kr + (((kg+4)^sw)<<3));
      f32x4 zz = {};
      zz   = __builtin_amdgcn_mfma_f32_16x16x32_bf16(kf0, qf0, zz, 0,0,0);
      sc[c]= __builtin_amdgcn_mfma_f32_16x16x32_bf16(kf1, qf1, zz, 0,0,0);
    }
    // row max over 16 in-lane + 2 cross-group shfls (lanes ln,ln+16,ln+32,ln+48 share q)
    float mx = fmaxf(fmaxf(fmaxf(sc[0][0],sc[0][1]),fmaxf(sc[0][2],sc[0][3])),
                     fmaxf(fmaxf(sc[1][0],sc[1][1]),fmaxf(sc[1][2],sc[1][3])));
    float mx2= fmaxf(fmaxf(fmaxf(sc[2][0],sc[2][1]),fmaxf(sc[2][2],sc[2][3])),
                     fmaxf(fmaxf(sc[3][0],sc[3][1]),fmaxf(sc[3][2],sc[3][3])));
    mx = fmaxf(mx, mx2);
    mx = fmaxf(mx, __shfl_xor(mx, 16));
    mx = fmaxf(mx, __shfl_xor(mx, 32));
    float mn = fmaxf(mrun, mx);
    float al = __expf(mrun - mn);
    mrun = mn;
    u32 pk[4][2];
    float sum = 0.f;
    #pragma unroll
    for (int c=0;c<4;c++){
      float p0 = __expf(sc[c][0]-mn), p1 = __expf(sc[c][1]-mn);
      float p2 = __expf(sc[c][2]-mn), p3 = __expf(sc[c][3]-mn);
      sum += (p0+p1)+(p2+p3);
      pk[c][0] = cvtpk(p0,p1);      // bf16 pair (k=c16+4kg+0, +1) for q=ln
      pk[c][1] = cvtpk(p2,p3);
    }
    sum += __shfl_xor(sum, 16);
    sum += __shfl_xor(sum, 32);
    lrun = lrun*al + sum;
    float alr0 = __shfl(al, kg*4+0), alr1 = __shfl(al, kg*4+1);
    float alr2 = __shfl(al, kg*4+2), alr3 = __shfl(al, kg*4+3);
    #pragma unroll
    for (int c=0;c<4;c++){ oc[c][0]*=alr0; oc[c][1]*=alr1; oc[c][2]*=alr2; oc[c][3]*=alr3; }
    // redistribute P into A-frags: lane needs P[q=ln][k=32kc+8kg+j] from
    // src lane 32*(kg&1)+ln (+16), reg c = 2kc + (kg>>1)
    int srcA = ((kg&1)<<5) + ln;
    int hi = kg >> 1;
    #pragma unroll
    for (int kc=0;kc<2;kc++){
      u32 a0 = (u32)__shfl((int)pk[2*kc  ][0], srcA   ), b0 = (u32)__shfl((int)pk[2*kc+1][0], srcA   );
      u32 a1 = (u32)__shfl((int)pk[2*kc  ][1], srcA   ), b1 = (u32)__shfl((int)pk[2*kc+1][1], srcA   );
      u32 a2 = (u32)__shfl((int)pk[2*kc  ][0], srcA+16), b2 = (u32)__shfl((int)pk[2*kc+1][0], srcA+16);
      u32 a3 = (u32)__shfl((int)pk[2*kc  ][1], srcA+16), b3 = (u32)__shfl((int)pk[2*kc+1][1], srcA+16);
      uint4 wv = make_uint4(hi? b0:a0, hi? b1:a1, hi? b2:a2, hi? b3:a3);
      bf16x8 af = __builtin_bit_cast(bf16x8, wv);
      #pragma unroll
      for (int c=0;c<4;c++){
        const u16* vr = Vb + (c*16+ln)*64;
        bf16x8 vf = *(const bf16x8*)(vr + (((kg+4*kc)^sw)<<3));
        oc[c] = __builtin_amdgcn_mfma_f32_16x16x32_bf16(af, vf, oc[c], 0,0,0);
      }
    }
  }
  int b = bh >> 4, h = bh & 15;
  float linv[4];
  linv[0] = 1.f/__shfl(lrun, kg*4+0); linv[1] = 1.f/__shfl(lrun, kg*4+1);
  linv[2] = 1.f/__shfl(lrun, kg*4+2); linv[3] = 1.f/__shfl(lrun, kg*4+3);
  #pragma unroll
  for (int r=0;r<4;r++){
    int srow = qt*64 + wid*16 + kg*4 + r;
    u16* op = attn + (size_t)(b*1024+srow)*DD + h*64;
    #pragma unroll
    for (int c=0;c<4;c++) op[c*16+ln] = f2b(oc[c][r]*linv[r]);
  }
}

// ---------------- launch ----------------
extern "C" void kernel_launch(void* const* d_in, const int* in_sizes, int n_in,
                              void* d_out, int out_size, void* d_ws, size_t ws_size,
                              hipStream_t stream){
  const float* x   = (const float*)d_in[0];
  const float* c   = (const float*)d_in[1];
  const float* n1w = (const float*)d_in[2];
  const float* n2w = (const float*)d_in[3];
  const float* wqkv= (const float*)d_in[4];
  const float* wout= (const float*)d_in[5];
  const float* w1  = (const float*)d_in[6];
  const float* b1  = (const float*)d_in[7];
  const float* w2  = (const float*)d_in[8];
  const float* b2  = (const float*)d_in[9];
  const float* aw  = (const float*)d_in[10];
  const float* ab  = (const float*)d_in[11];
  const float* cosb= (const float*)d_in[12];
  const float* sinb= (const float*)d_in[13];

  const size_t REQ = 117538816;
  if (ws_size < REQ){
    k_zero<<<4096,256,0,stream>>>((float*)d_out);   // sentinel: absmax==5.03 => ws too small
    return;
  }
  char* ws = (char*)d_ws;
  u16*   wqkvT = (u16*)(ws + 0);
  u16*   woutT = (u16*)(ws + 6291456);
  u16*   act   = (u16*)(ws + 8388608);
  float* mod   = (float*)(ws + 16777216);
  float* x2    = (float*)(ws + 16875520);
  u16*   qh    = (u16*)(ws + 16875520);
  u16*   kh    = (u16*)(ws + 25264128);
  u16*   vt    = (u16*)(ws + 33652736);    // 8 MB (b,h,d,s), written by QKV epilogue
  u16*   part2b= (u16*)(ws + 33652736);    // 16 MB bf16 (over vt, dead after attn)
  u16*   hbuf  = (u16*)(ws + 33652736);    // 32 MB bf16 (after red_ln)
  u16*   w1T   = (u16*)(ws + 67207168);
  u16*   w2T   = (u16*)(ws + 75595776);
  u16*   part4b= (u16*)(ws + 83984384);    // 32 MB bf16

  k_prep<<<12384,256,0,stream>>>(wqkv, wout, w1, w2, wqkvT, woutT, w1T, w2T, c, aw, ab, mod);
  k_ln_mod<<<4096,256,0,stream>>>(x, n1w, mod, 0*DD, 1*DD, act);
  k_gemm256<EPI_QKV ><<<dim3(16,12,1),512,0,stream>>>(act, wqkvT, 4096,3072,1024,1024,
        nullptr, nullptr, cosb, sinb, qh, kh, vt);
  k_attn<<<1024,256,0,stream>>>(qh, kh, vt, act);
  // attn proj: split-K x2, bf16 partials, fused reduce+resid+LN2+modulate
  k_gemm256<EPI_PARTB><<<dim3(16,4,2),512,0,stream>>>(act, woutT, 4096,1024,512,1024,
        nullptr, part2b, nullptr, nullptr, nullptr, nullptr, nullptr);
  k_red_ln<<<4096,256,0,stream>>>(part2b, x, mod, n2w, x2, act);
  k_gemm256<EPI_GELU><<<dim3(16,16,1),512,0,stream>>>(act, w1T, 4096,4096,1024,1024,
        b1, hbuf, nullptr, nullptr, nullptr, nullptr, nullptr);
  // mlp2: split-K x4 (bf16 partials), reduce -> d_out
  k_gemm256<EPI_PARTB><<<dim3(16,4,4),512,0,stream>>>(hbuf, w2T, 4096,1024,1024,4096,
        nullptr, part4b, nullptr, nullptr, nullptr, nullptr, nullptr);
  k_reduce4b<<<4096,256,0,stream>>>(part4b, (size_t)4096*1024, x2, mod, 5*DD, b2, (float*)d_out);
}